// Round 14
// baseline (97.314 us; speedup 1.0000x reference)
//
#include <hip/hip_runtime.h>
#include <hip/hip_bf16.h>

#define HEADS 16
#define SEQ   4096
#define DIM   64
#define QT    64
#define KT    64
#define SCALE 0.125f
// SCALE * log2(e): folded into Q at conversion so scores are in log2 domain
#define CF    0.18033688011112042f
#define LOG2E 1.4426950408889634f

typedef __bf16 v8bf  __attribute__((ext_vector_type(8)));
typedef __bf16 v4bf  __attribute__((ext_vector_type(4)));
typedef float  f32x4 __attribute__((ext_vector_type(4)));

__device__ __forceinline__ __bf16 to_bf(float f) { return (__bf16)f; }
// v_exp_f32 computes 2^x; v_log_f32 computes log2(x)
__device__ __forceinline__ float ex2(float x) { return __builtin_amdgcn_exp2f(x); }
__device__ __forceinline__ float lg2(float x) { return __builtin_amdgcn_logf(x); }

__device__ __forceinline__ void gload16(const __bf16* g, __bf16* l) {
    __builtin_amdgcn_global_load_lds(
        (const __attribute__((address_space(1))) void*)g,
        (__attribute__((address_space(3))) void*)l,
        16, 0, 0);
}

// ===========================================================================
// Fused pre-pass (one launch): z=0 K [h][d][s] -> Kb [h][t][d];
// z=1 V [h][s][d] -> Vb [h][d][perm(t)]; z=2 Q scale-convert (CF folded).
// ===========================================================================
__global__ __launch_bounds__(256) void conv_fused_kernel(
    const float* __restrict__ qg, const float* __restrict__ kg,
    const float* __restrict__ vg, __bf16* __restrict__ Qb,
    __bf16* __restrict__ Kb, __bf16* __restrict__ Vb)
{
    __shared__ __bf16 ldsT[64][65];
    const int h   = blockIdx.y;
    const int t0  = blockIdx.x * 64;
    const int tid = threadIdx.x;
    const int rr  = tid >> 2;          // 0..63
    const int cq  = (tid & 3) * 16;    // 0,16,32,48

    if (blockIdx.z == 2) {
        const float* src = qg + ((size_t)h * SEQ + t0 + rr) * DIM + cq;
        __bf16* dst = Qb + ((size_t)h * SEQ + t0 + rr) * DIM + cq;
        v8bf o0, o1;
        #pragma unroll
        for (int j = 0; j < 2; ++j) {
            float4 f0 = *(const float4*)(src + 8 * j);
            float4 f1 = *(const float4*)(src + 8 * j + 4);
            v8bf o;
            o[0] = to_bf(f0.x * CF); o[1] = to_bf(f0.y * CF);
            o[2] = to_bf(f0.z * CF); o[3] = to_bf(f0.w * CF);
            o[4] = to_bf(f1.x * CF); o[5] = to_bf(f1.y * CF);
            o[6] = to_bf(f1.z * CF); o[7] = to_bf(f1.w * CF);
            if (j == 0) o0 = o; else o1 = o;
        }
        *(v8bf*)dst = o0;
        *(v8bf*)(dst + 8) = o1;
        return;
    }

    if (blockIdx.z == 0) {
        const float* src = kg + ((size_t)h * DIM + rr) * SEQ + t0 + cq;  // d=rr
        #pragma unroll
        for (int j = 0; j < 4; ++j) {
            float4 f = *(const float4*)(src + 4 * j);
            ldsT[rr][cq + 4 * j + 0] = to_bf(f.x);
            ldsT[rr][cq + 4 * j + 1] = to_bf(f.y);
            ldsT[rr][cq + 4 * j + 2] = to_bf(f.z);
            ldsT[rr][cq + 4 * j + 3] = to_bf(f.w);
        }
        __syncthreads();
        __bf16* dst = Kb + (size_t)h * SEQ * DIM + (size_t)(t0 + rr) * DIM + cq;
        v8bf o0, o1;
        #pragma unroll
        for (int i = 0; i < 8; ++i) {
            o0[i] = ldsT[cq + i][rr];
            o1[i] = ldsT[cq + 8 + i][rr];
        }
        *(v8bf*)dst = o0;
        *(v8bf*)(dst + 8) = o1;
    } else {
        const float* src = vg + ((size_t)h * SEQ + t0 + rr) * DIM + cq;  // t=rr
        #pragma unroll
        for (int j = 0; j < 4; ++j) {
            float4 f = *(const float4*)(src + 4 * j);
            ldsT[rr][cq + 4 * j + 0] = to_bf(f.x);
            ldsT[rr][cq + 4 * j + 1] = to_bf(f.y);
            ldsT[rr][cq + 4 * j + 2] = to_bf(f.z);
            ldsT[rr][cq + 4 * j + 3] = to_bf(f.w);
        }
        __syncthreads();
        __bf16* dst0 = Vb + ((size_t)h * DIM + rr) * SEQ + t0;
        const int n  = cq >> 4;
        const int c0 = 32 * (n >> 1) + 4 * (n & 1);
        #pragma unroll
        for (int j2 = 0; j2 < 4; ++j2) {
            v4bf ch;
            #pragma unroll
            for (int r = 0; r < 4; ++r)
                ch[r] = ldsT[cq + 4 * j2 + r][rr];
            *(v4bf*)(dst0 + c0 + 8 * j2) = ch;
        }
    }
}

// ===========================================================================
// Pass A v11: round-11 structure (8-wave blocks, intra-block key-split,
// shared ds_reads) with the phase-serialization fix: NO setprio fences in
// the loop, and the visit is software-pipelined as
//   QK(all) -> exp/pack(n0,n1) -> PV(kk=0) -> exp/pack(n2,n3) -> PV(kk=1)
// so PV MFMAs overlap the second half's exp/pack VALU work.
// ===========================================================================
__global__ __launch_bounds__(512, 4) void fa_fwd8_kernel(
    const __bf16* __restrict__ Qb, const __bf16* __restrict__ Kb,
    const __bf16* __restrict__ Vb, float* __restrict__ outg,
    float* __restrict__ lseg)
{
    const int b    = blockIdx.x;
    const int xcd  = b & 7;
    const int j    = b >> 3;           // 0..63
    const int h    = 2 * xcd + (j & 1);
    const int a    = j >> 1;           // 0..31: qtile pair (a, 63-a)
    const int tid  = threadIdx.x;      // 0..511
    const int wave = tid >> 6;         // 0..7
    const int lane = tid & 63;
    const int g    = lane >> 4;
    const int l16  = lane & 15;
    const int grp  = wave >> 2;        // 0: even subtiles; 1: odd subtiles
    const int w4   = wave & 3;
    const int wit  = w4 * 16 + l16;    // q-row within a qtile

    const int qlo = a;
    const int qhi = 63 - a;
    const int NT  = 64 - a;
    const int nIt = (NT + 1) >> 1;

    __shared__ alignas(16) __bf16 ldsPool[32768];

    const int r0 = tid >> 3;           // 0..63
    const int c0 = tid & 7;
    const size_t kOff = (size_t)r0 * DIM + (size_t)((c0 ^ (r0 & 7)) << 3);
    const size_t vOff = (size_t)r0 * SEQ + (size_t)((c0 ^ (r0 & 7)) << 3);
    const __bf16* KbH = Kb + (size_t)h * SEQ * DIM;
    const __bf16* VbH = Vb + (size_t)h * DIM * SEQ;
    const int ldsW = wave * 512;

    const int qLoRow = qlo * QT + wit;
    const int qHiRow = qhi * QT + wit;
    const __bf16* qlr = Qb + ((size_t)h * SEQ + qLoRow) * DIM + g * 8;
    const __bf16* qhr = Qb + ((size_t)h * SEQ + qHiRow) * DIM + g * 8;
    v8bf aqlo0 = *(const v8bf*)qlr;
    v8bf aqlo1 = *(const v8bf*)(qlr + 32);
    v8bf aqhi0 = *(const v8bf*)qhr;
    v8bf aqhi1 = *(const v8bf*)(qhr + 32);

    f32x4 accl[4], acch[4];
    #pragma unroll
    for (int n = 0; n < 4; ++n) {
        accl[n] = (f32x4){0.f, 0.f, 0.f, 0.f};
        acch[n] = (f32x4){0.f, 0.f, 0.f, 0.f};
    }
    float lpl[4] = {0.f, 0.f, 0.f, 0.f};
    float lph[4] = {0.f, 0.f, 0.f, 0.f};

    int cur = 0;
    #pragma unroll
    for (int u = 0; u < 2; ++u) {
        gload16(KbH + (size_t)(64 * u) * DIM + kOff,
                ldsPool + (size_t)u * 4096 + ldsW);
        gload16(VbH + 64 * u + vOff,
                ldsPool + 16384 + (size_t)u * 4096 + ldsW);
    }
    __syncthreads();

    #pragma unroll 1
    for (int it = 0; it < nIt; ++it) {
        if (it + 1 < nIt) {
            const int nbuf = cur ^ 1;
            #pragma unroll
            for (int u = 0; u < 2; ++u) {
                gload16(KbH + (size_t)(128 * (it + 1) + 64 * u) * DIM + kOff,
                        ldsPool + (size_t)(nbuf * 2 + u) * 4096 + ldsW);
                gload16(VbH + (128 * (it + 1) + 64 * u) + vOff,
                        ldsPool + 16384 + (size_t)(nbuf * 2 + u) * 4096 + ldsW);
            }
        }
        const int t = 2 * it + grp;
        if (t <= qhi) {
            const __bf16* Kt = ldsPool + (size_t)(cur * 2 + grp) * 4096;
            const __bf16* Vt = ldsPool + 16384 + (size_t)(cur * 2 + grp) * 4096;
            if (t <= qlo) {
                // ================= FULL: both Q-groups =================
                f32x4 sl[4], sh[4];
                #pragma unroll
                for (int n = 0; n < 4; ++n) {
                    sl[n] = (f32x4){0.f, 0.f, 0.f, 0.f};
                    sh[n] = (f32x4){0.f, 0.f, 0.f, 0.f};
                }
                // ---- QK (all)
                #pragma unroll
                for (int kk = 0; kk < 2; ++kk) {
                    #pragma unroll
                    for (int n = 0; n < 4; ++n) {
                        int row  = 16 * n + l16;
                        int byte = row * 128 + kk * 64 + g * 16;
                        byte ^= (row & 7) << 4;
                        v8bf ak = *(const v8bf*)&Kt[byte >> 1];
                        sl[n] = __builtin_amdgcn_mfma_f32_16x16x32_bf16(
                            ak, kk ? aqlo1 : aqlo0, sl[n], 0, 0, 0);
                        sh[n] = __builtin_amdgcn_mfma_f32_16x16x32_bf16(
                            ak, kk ? aqhi1 : aqhi0, sh[n], 0, 0, 0);
                    }
                }
                if (t == qlo) {
                    #pragma unroll
                    for (int n = 0; n < 4; ++n)
                        #pragma unroll
                        for (int r = 0; r < 4; ++r)
                            if (16 * n + 4 * g + r > wit) sl[n][r] = -3.0e38f;
                }
                // ---- exp/pack n0,n1 -> pl0/ph0
                v8bf pl0, ph0;
                #pragma unroll
                for (int n = 0; n < 2; ++n)
                    #pragma unroll
                    for (int r = 0; r < 4; ++r) {
                        float p = ex2(sl[n][r]);
                        float q = ex2(sh[n][r]);
                        lpl[r] += p; lph[r] += q;
                        pl0[n * 4 + r] = to_bf(p);
                        ph0[n * 4 + r] = to_bf(q);
                    }
                // ---- PV kk=0 (overlaps next exp block)
                #pragma unroll
                for (int n = 0; n < 4; ++n) {
                    int row  = 16 * n + l16;
                    int byte = row * 128 + g * 16;
                    byte ^= (row & 7) << 4;
                    v8bf av = *(const v8bf*)&Vt[byte >> 1];
                    accl[n] = __builtin_amdgcn_mfma_f32_16x16x32_bf16(
                        av, pl0, accl[n], 0, 0, 0);
                    acch[n] = __builtin_amdgcn_mfma_f32_16x16x32_bf16(
                        av, ph0, acch[n], 0, 0, 0);
                }
                // ---- exp/pack n2,n3 -> pl1/ph1
                v8bf pl1, ph1;
                #pragma unroll
                for (int n = 2; n < 4; ++n)
                    #pragma unroll
                    for (int r = 0; r < 4; ++r) {
                        float p = ex2(sl[n][r]);
                        float q = ex2(sh[n][r]);
                        lpl[r] += p; lph[r] += q;
                        pl1[(n & 1) * 4 + r] = to_bf(p);
                        ph1[(n & 1) * 4 + r] = to_bf(q);
                    }
                // ---- PV kk=1
                #pragma unroll
                for (int n = 0; n < 4; ++n) {
                    int row  = 16 * n + l16;
                    int byte = row * 128 + 64 + g * 16;
                    byte ^= (row & 7) << 4;
                    v8bf av = *(const v8bf*)&Vt[byte >> 1];
                    accl[n] = __builtin_amdgcn_mfma_f32_16x16x32_bf16(
                        av, pl1, accl[n], 0, 0, 0);
                    acch[n] = __builtin_amdgcn_mfma_f32_16x16x32_bf16(
                        av, ph1, acch[n], 0, 0, 0);
                }
            } else {
                // ================= HI only =================
                f32x4 sh[4];
                #pragma unroll
                for (int n = 0; n < 4; ++n) sh[n] = (f32x4){0.f, 0.f, 0.f, 0.f};
                #pragma unroll
                for (int kk = 0; kk < 2; ++kk) {
                    #pragma unroll
                    for (int n = 0; n < 4; ++n) {
                        int row  = 16 * n + l16;
                        int byte = row * 128 + kk * 64 + g * 16;
                        byte ^= (row & 7) << 4;
                        v8bf ak = *(const v8bf*)&Kt[byte >> 1];
                        sh[n] = __builtin_amdgcn_mfma_f32_16x16x32_bf16(
                            ak, kk ? aqhi1 : aqhi0, sh[n], 0, 0, 0);
                    }
                }
                if (t == qhi) {
                    #pragma unroll
                    for (int n = 0; n < 4; ++n)
                        #pragma unroll
                        for (int r = 0; r < 4; ++r)
                            if (16 * n + 4 * g + r > wit) sh[n][r] = -3.0e38f;
                }
                v8bf ph0;
                #pragma unroll
                for (int n = 0; n < 2; ++n)
                    #pragma unroll
                    for (int r = 0; r < 4; ++r) {
                        float q = ex2(sh[n][r]);
                        lph[r] += q;
                        ph0[n * 4 + r] = to_bf(q);
                    }
                #pragma unroll
                for (int n = 0; n < 4; ++n) {
                    int row  = 16 * n + l16;
                    int byte = row * 128 + g * 16;
                    byte ^= (row & 7) << 4;
                    v8bf av = *(const v8bf*)&Vt[byte >> 1];
                    acch[n] = __builtin_amdgcn_mfma_f32_16x16x32_bf16(
                        av, ph0, acch[n], 0, 0, 0);
                }
                v8bf ph1;
                #pragma unroll
                for (int n = 2; n < 4; ++n)
                    #pragma unroll
                    for (int r = 0; r < 4; ++r) {
                        float q = ex2(sh[n][r]);
                        lph[r] += q;
                        ph1[(n & 1) * 4 + r] = to_bf(q);
                    }
                #pragma unroll
                for (int n = 0; n < 4; ++n) {
                    int row  = 16 * n + l16;
                    int byte = row * 128 + 64 + g * 16;
                    byte ^= (row & 7) << 4;
                    v8bf av = *(const v8bf*)&Vt[byte >> 1];
                    acch[n] = __builtin_amdgcn_mfma_f32_16x16x32_bf16(
                        av, ph1, acch[n], 0, 0, 0);
                }
            }
        }
        __syncthreads();
        cur ^= 1;
    }

    // ---- combine partials across the grp pair through LDS scratch
    float* scratch = (float*)ldsPool;
    {
        float* sp = scratch + (size_t)(grp ? (4 + w4) : w4) * 1280;
        if (grp == 0) {
            #pragma unroll
            for (int n = 0; n < 4; ++n)
                #pragma unroll
                for (int r = 0; r < 4; ++r)
                    sp[(n * 4 + r) * 64 + lane] = acch[n][r];
            #pragma unroll
            for (int r = 0; r < 4; ++r) sp[(16 + r) * 64 + lane] = lph[r];
        } else {
            #pragma unroll
            for (int n = 0; n < 4; ++n)
                #pragma unroll
                for (int r = 0; r < 4; ++r)
                    sp[(n * 4 + r) * 64 + lane] = accl[n][r];
            #pragma unroll
            for (int r = 0; r < 4; ++r) sp[(16 + r) * 64 + lane] = lpl[r];
        }
    }
    __syncthreads();
    f32x4 accO[4];
    float lpO[4];
    {
        const float* op = scratch + (size_t)(grp ? w4 : (4 + w4)) * 1280;
        if (grp == 0) {
            #pragma unroll
            for (int n = 0; n < 4; ++n)
                #pragma unroll
                for (int r = 0; r < 4; ++r)
                    accO[n][r] = accl[n][r] + op[(n * 4 + r) * 64 + lane];
            #pragma unroll
            for (int r = 0; r < 4; ++r)
                lpO[r] = lpl[r] + op[(16 + r) * 64 + lane];
        } else {
            #pragma unroll
            for (int n = 0; n < 4; ++n)
                #pragma unroll
                for (int r = 0; r < 4; ++r)
                    accO[n][r] = acch[n][r] + op[(n * 4 + r) * 64 + lane];
            #pragma unroll
            for (int r = 0; r < 4; ++r)
                lpO[r] = lph[r] + op[(16 + r) * 64 + lane];
        }
    }

    const int q = (grp ? qhi : qlo) * QT + wit;
    float l = (lpO[0] + lpO[1]) + (lpO[2] + lpO[3]);
    l += __shfl_xor(l, 16);
    l += __shfl_xor(l, 32);
    const float inv = 1.0f / l;
    float* orow = outg + ((size_t)h * SEQ + q) * DIM;
    #pragma unroll
    for (int n = 0; n < 4; ++n) {
        f32x4 o = accO[n];
        o[0] *= inv; o[1] *= inv; o[2] *= inv; o[3] *= inv;
        *(f32x4*)(orow + 16 * n + 4 * g) = o;
    }
    if (g == 0)
        lseg[h * SEQ + q] = lg2(l);
}

// ===========================================================================
// Pass B v6: 8-wave colsum, no setprio fences; exp-A overlaps QK-B.
// ===========================================================================
__global__ __launch_bounds__(512, 4) void fa_colsum8_kernel(
    const __bf16* __restrict__ Qb, const __bf16* __restrict__ Kb,
    const float* __restrict__ lseg, float* __restrict__ rsg)
{
    const int b    = blockIdx.x;
    const int xcd  = b & 7;
    const int j    = b >> 3;
    const int h    = 2 * xcd + (j & 1);
    const int ta   = j >> 1;            // 0..31
    const int tb   = 63 - ta;
    const int tid  = threadIdx.x;       // 0..511
    const int wave = tid >> 6;          // 0..7
    const int lane = tid & 63;
    const int g    = lane >> 4;
    const int l16  = lane & 15;
    const int grp  = wave >> 2;         // qt parity
    const int w4   = wave & 3;          // q-slice within qtile

    __shared__ alignas(16) __bf16 ldsK2[2][KT * DIM];   // 16 KB
    __shared__ float cs[2][8][KT];                      // 4 KB

    const int r0 = tid >> 3;            // 0..63
    const int c0 = tid & 7;
    const size_t kOff = (size_t)r0 * DIM + (size_t)((c0 ^ (r0 & 7)) << 3);
    const __bf16* KbH  = Kb + (size_t)h * SEQ * DIM;
    const __bf16* QbH  = Qb + (size_t)h * SEQ * DIM;
    const float*  lseH = lseg + (size_t)h * SEQ;
    const int ldsW = wave * 512;

    gload16(KbH + (size_t)ta * KT * DIM + kOff, &ldsK2[0][ldsW]);
    gload16(KbH + (size_t)tb * KT * DIM + kOff, &ldsK2[1][ldsW]);

    float accA[4] = {0.f, 0.f, 0.f, 0.f};
    float accB[4] = {0.f, 0.f, 0.f, 0.f};

    const int qstart = ta + grp;
    v8bf aq0, aq1;
    float4 lse4;
    {
        const int qw = qstart * QT + w4 * 16;
        const __bf16* qrow = QbH + (size_t)(qw + l16) * DIM + g * 8;
        aq0  = *(const v8bf*)qrow;
        aq1  = *(const v8bf*)(qrow + 32);
        lse4 = *(const float4*)(lseH + qw + 4 * g);
    }
    __syncthreads();                    // K tiles staged (drains vmcnt)

    #pragma unroll 1
    for (int qt = qstart; qt < SEQ / QT; qt += 2) {
        v8bf naq0, naq1;
        float4 nlse4;
        const bool more = (qt + 2 < SEQ / QT);
        if (more) {
            const int qw2 = (qt + 2) * QT + w4 * 16;
            const __bf16* qrow2 = QbH + (size_t)(qw2 + l16) * DIM + g * 8;
            naq0  = *(const v8bf*)qrow2;
            naq1  = *(const v8bf*)(qrow2 + 32);
            nlse4 = *(const float4*)(lseH + qw2 + 4 * g);
        }
        const int qw = qt * QT + w4 * 16;
        const bool bAct = (qt >= tb);   // wave-uniform

        // ---- QK tile A
        f32x4 sA[4];
        #pragma unroll
        for (int n = 0; n < 4; ++n) sA[n] = (f32x4){0.f, 0.f, 0.f, 0.f};
        #pragma unroll
        for (int kk = 0; kk < 2; ++kk)
            #pragma unroll
            for (int n = 0; n < 4; ++n) {
                int row  = 16 * n + l16;
                int byte = row * 128 + kk * 64 + g * 16;
                byte ^= (row & 7) << 4;
                v8bf bk = *(const v8bf*)&ldsK2[0][byte >> 1];
                sA[n] = __builtin_amdgcn_mfma_f32_16x16x32_bf16(
                    kk ? aq1 : aq0, bk, sA[n], 0, 0, 0);
            }
        if (bAct) {
            // ---- QK tile B (exp-A below can overlap these chains)
            f32x4 sB[4];
            #pragma unroll
            for (int n = 0; n < 4; ++n) sB[n] = (f32x4){0.f, 0.f, 0.f, 0.f};
            #pragma unroll
            for (int kk = 0; kk < 2; ++kk)
                #pragma unroll
                for (int n = 0; n < 4; ++n) {
                    int row  = 16 * n + l16;
                    int byte = row * 128 + kk * 64 + g * 16;
                    byte ^= (row & 7) << 4;
                    v8bf bk = *(const v8bf*)&ldsK2[1][byte >> 1];
                    sB[n] = __builtin_amdgcn_mfma_f32_16x16x32_bf16(
                        kk ? aq1 : aq0, bk, sB[n], 0, 0, 0);
                }
            // ---- exp A
            #pragma unroll
            for (int n = 0; n < 4; ++n)
                #pragma unroll
                for (int r = 0; r < 4; ++r)
                    accA[n] += ex2(sA[n][r] - lse4[r]);
            // ---- exp B (diag masking only when qt==tb)
            if (qt == tb) {
                #pragma unroll
                for (int n = 0; n < 4; ++n) {
                    const int key = tb * KT + 16 * n + l16;
                    #pragma unroll
                    for (int r = 0; r < 4; ++r) {
                        float e = ex2(sB[n][r] - lse4[r]);
                        accB[n] += (key <= qw + 4 * g + r) ? e : 0.f;
                    }
                }
            } else {
                #pragma unroll
                for (int n = 0; n < 4; ++n)
                    #pragma unroll
                    for (int r = 0; r < 4; ++r)
                        accB[n] += ex2(sB[n][r] - lse4[r]);
            }
        } else {
            // ---- exp A only (diag masking only when qt==ta)
            if (qt == ta) {
                #pragma unroll
                for (int n = 0; n < 4; ++n) {
                    const int key = ta * KT + 16 * n + l16;
                    #pragma unroll
                    for (int r = 0; r < 4; ++r) {
                        float e = ex2(sA[n][r] - lse4[r]);
                        accA[n] += (key <= qw + 4 * g + r) ? e : 0.f;
                    }
                }
            } else {
                #pragma unroll
                for (int n = 0; n < 4; ++n)
                    #pragma unroll
                    for (int r = 0; r < 4; ++r)
                        accA[n] += ex2(sA[n][r] - lse4[r]);
            }
        }
        if (more) { aq0 = naq0; aq1 = naq1; lse4 = nlse4; }
    }

    #pragma unroll
    for (int n = 0; n < 4; ++n) {
        accA[n] += __shfl_xor(accA[n], 16);
        accA[n] += __shfl_xor(accA[n], 32);
        accB[n] += __shfl_xor(accB[n], 16);
        accB[n] += __shfl_xor(accB[n], 32);
    }
    if (lane < 16) {
        #pragma unroll
        for (int n = 0; n < 4; ++n) {
            cs[0][wave][16 * n + lane] = accA[n];
            cs[1][wave][16 * n + lane] = accB[n];
        }
    }
    __syncthreads();
    if (tid < KT) {
        float v = 0.f;
        #pragma unroll
        for (int w = 0; w < 8; ++w) v += cs[0][w][tid];
        rsg[(size_t)h * SEQ + ta * KT + tid] = v;
    } else if (tid < 2 * KT) {
        const int t = tid - KT;
        float v = 0.f;
        #pragma unroll
        for (int w = 0; w < 8; ++w) v += cs[1][w][t];
        rsg[(size_t)h * SEQ + tb * KT + t] = v;
    }
}

// ===========================================================================
// Fallback (round-1, fp32 inputs, scalar staging) — used if ws too small.
// ===========================================================================
__global__ __launch_bounds__(256, 1) void fa_fwd_v1_kernel(
    const float* __restrict__ qg, const float* __restrict__ kg,
    const float* __restrict__ vg, float* __restrict__ outg,
    float* __restrict__ lseg)
{
    const int h    = blockIdx.y;
    const int q0   = blockIdx.x * QT;
    const int tid  = threadIdx.x;
    const int wave = tid >> 6;
    const int lane = tid & 63;
    const int g    = lane >> 4;
    const int l16  = lane & 15;

    __shared__ alignas(16) __bf16 ldsK[KT * DIM];
    __shared__ alignas(16) __bf16 ldsV[DIM * KT];
    __shared__ alignas(16) __bf16 ldsP[4][16 * 72];

    const int qw = q0 + wave * 16;
    v8bf aq[2];
    {
        const float* qrow = qg + ((size_t)h * SEQ + qw + l16) * DIM;
        #pragma unroll
        for (int kk = 0; kk < 2; ++kk) {
            const float* p = qrow + kk * 32 + g * 8;
            float4 f0 = *(const float4*)p;
            float4 f1 = *(const float4*)(p + 4);
            aq[kk][0] = to_bf(f0.x); aq[kk][1] = to_bf(f0.y);
            aq[kk][2] = to_bf(f0.z); aq[kk][3] = to_bf(f0.w);
            aq[kk][4] = to_bf(f1.x); aq[kk][5] = to_bf(f1.y);
            aq[kk][6] = to_bf(f1.z); aq[kk][7] = to_bf(f1.w);
        }
    }
    f32x4 acc[4];
    #pragma unroll
    for (int n = 0; n < 4; ++n) acc[n] = (f32x4){0.f, 0.f, 0.f, 0.f};
    float m_r[4], l_r[4];
    #pragma unroll
    for (int r = 0; r < 4; ++r) { m_r[r] = -__builtin_inff(); l_r[r] = 0.f; }

    const int ntiles = q0 / KT + 1;
    const int kd = tid >> 2;
    const int kc = (tid & 3) * 16;

    for (int t = 0; t < ntiles; ++t) {
        const int t0 = t * KT;
        __syncthreads();
        {
            const float* src = kg + ((size_t)h * DIM + kd) * SEQ + t0 + kc;
            #pragma unroll
            for (int j = 0; j < 4; ++j) {
                float4 f = *(const float4*)(src + 4 * j);
                #pragma unroll
                for (int i = 0; i < 4; ++i) {
                    int row  = kc + 4 * j + i;
                    int byte = row * 128 + kd * 2;
                    byte ^= (row & 7) << 4;
                    ldsK[byte >> 1] = to_bf(((const float*)&f)[i]);
                }
            }
        }
        {
            const float* src = vg + ((size_t)h * SEQ + t0 + kd) * DIM + kc;
            #pragma unroll
            for (int j = 0; j < 4; ++j) {
                float4 f = *(const float4*)(src + 4 * j);
                #pragma unroll
                for (int i = 0; i < 4; ++i) {
                    int row  = kc + 4 * j + i;
                    int byte = row * 128 + kd * 2;
                    byte ^= (row & 7) << 4;
                    ldsV[byte >> 1] = to_bf(((const float*)&f)[i]);
                }
            }
        }
        __syncthreads();

        f32x4 s[4];
        #pragma unroll
        for (int n = 0; n < 4; ++n) s[n] = (f32x4){0.f, 0.f, 0.f, 0.f};
        #pragma unroll
        for (int kk = 0; kk < 2; ++kk)
            #pragma unroll
            for (int n = 0; n < 4; ++n) {
                int row  = 16 * n + l16;
                int byte = row * 128 + kk * 64 + g * 16;
                byte ^= (row & 7) << 4;
                v8bf bk = *(const v8bf*)&ldsK[byte >> 1];
                s[n] = __builtin_amdgcn_mfma_f32_16x16x32_bf16(aq[kk], bk, s[n], 0, 0, 0);
            }
        float pvv[4][4];
        #pragma unroll
        for (int r = 0; r < 4; ++r) {
            const int qq = qw + 4 * g + r;
            float sv[4];
            #pragma unroll
            for (int n = 0; n < 4; ++n) {
                int key = t0 + 16 * n + l16;
                sv[n] = (key <= qq) ? s[n][r] * (SCALE * LOG2E) : -3.0e38f;
            }
            float mx = fmaxf(fmaxf(sv[0], sv[1]), fmaxf(sv[2], sv[3]));
            mx = fmaxf(mx, __shfl_xor(mx, 1));
            mx = fmaxf(mx, __shfl_xor(mx, 2));
            mx = fmaxf(mx, __shfl_xor(mx, 4));
            mx = fmaxf(mx, __shfl_xor(mx, 8));
            float mnew = fmaxf(m_r[r], mx);
            float corr = ex2(m_r[r] - mnew);
            m_r[r] = mnew;
            float rs = 0.f;
            #pragma unroll
            for (int n = 0; n < 4; ++n) {
                float p = (sv[n] > -1.0e38f) ? ex2(sv[n] - mnew) : 0.f;
                pvv[n][r] = p;
                rs += p;
            }
            rs += __shfl_xor(rs, 1);
            rs += __shfl_xor(rs, 2);
            rs += __shfl_xor(rs, 4);
            rs += __shfl_xor(rs, 8);
            l_r[r] = l_r[r] * corr + rs;
            #pragma unroll
            for (int n = 0; n < 4; ++n) acc[n][r] *= corr;
        }
        #pragma unroll
        for (int n = 0; n < 4; ++n)
            #pragma unroll
            for (int r = 0; r < 4; ++r)
                ldsP[wave][(4 * g + r) * 72 + 16 * n + l16] = to_bf(pvv[n][r]);
        asm volatile("s_waitcnt lgkmcnt(0)" ::: "memory");
        __builtin_amdgcn_sched_barrier(0);
        #pragma unroll
        for (int kk = 0; kk < 2; ++kk) {
            v8bf ap = *(const v8bf*)&ldsP[wave][l16 * 72 + 32 * kk + 8 * g];
            #pragma unroll
            for (int n = 0; n < 4; ++n) {
                int row  = 16 * n + l16;
                int byte = row * 128 + kk * 64 + g * 16;
                byte ^= (row & 7) << 4;
                v8bf bv = *(const v8bf*)&ldsV[byte >> 1];
                acc[n] = __builtin_amdgcn_mfma_f32_16x16x32_bf16(ap, bv, acc[n], 0, 0, 0);
            }
        }
    }
    #pragma unroll
    for (int r = 0; r < 4; ++r) {
        const int qq  = qw + 4 * g + r;
        const float inv = 1.0f / l_r[r];
        float* orow = outg + ((size_t)h * SEQ + qq) * DIM;
        #pragma unroll
        for (int n = 0; n < 4; ++n)
            orow[16 * n + l16] = acc[n][r] * inv;
        if (l16 == 0)
            lseg[h * SEQ + qq] = m_r[r] + lg2(l_r[r]);
    }
}

__global__ __launch_bounds__(256, 1) void fa_colsum_v1_kernel(
    const float* __restrict__ qg, const float* __restrict__ kg,
    const float* __restrict__ lseg, float* __restrict__ rsg)
{
    const int h    = blockIdx.y;
    const int t0   = blockIdx.x * KT;
    const int tid  = threadIdx.x;
    const int wave = tid >> 6;
    const int lane = tid & 63;
    const int g    = lane >> 4;
    const int l16  = lane & 15;

    __shared__ alignas(16) __bf16 ldsK[KT * DIM];
    __shared__ float cs[4][KT];
    {
        const int kd = tid >> 2;
        const int kc = (tid & 3) * 16;
        const float* src = kg + ((size_t)h * DIM + kd) * SEQ + t0 + kc;
        #pragma unroll
        for (int j = 0; j < 4; ++j) {
            float4 f = *(const float4*)(src + 4 * j);
            #pragma unroll
            for (int i = 0; i < 4; ++i) {
                int row  = kc + 4 * j + i;
                int byte = row * 128 + kd * 2;
                byte ^= (row & 7) << 4;
                ldsK[byte >> 1] = to_bf(((const float*)&f)[i]);
            }
        }
    }
    __syncthreads();
    float colacc[4] = {0.f, 0.f, 0.f, 0.f};
    for (int qt = t0 / QT; qt < SEQ / QT; ++qt) {
        const int qw = qt * QT + wave * 16;
        const float* qrow = qg + ((size_t)h * SEQ + qw + l16) * DIM;
        v8bf aq[2];
        #pragma unroll
        for (int kk = 0; kk < 2; ++kk) {
            const float* p = qrow + kk * 32 + g * 8;
            float4 f0 = *(const float4*)p;
            float4 f1 = *(const float4*)(p + 4);
            aq[kk][0] = to_bf(f0.x); aq[kk][1] = to_bf(f0.y);
            aq[kk][2] = to_bf(f0.z); aq[kk][3] = to_bf(f0.w);
            aq[kk][4] = to_bf(f1.x); aq[kk][5] = to_bf(f1.y);
            aq[kk][6] = to_bf(f1.z); aq[kk][7] = to_bf(f1.w);
        }
        float lse_r[4];
        #pragma unroll
        for (int r = 0; r < 4; ++r)
            lse_r[r] = lseg[h * SEQ + qw + 4 * g + r];
        f32x4 s[4];
        #pragma unroll
        for (int n = 0; n < 4; ++n) s[n] = (f32x4){0.f, 0.f, 0.f, 0.f};
        #pragma unroll
        for (int kk = 0; kk < 2; ++kk)
            #pragma unroll
            for (int n = 0; n < 4; ++n) {
                int row  = 16 * n + l16;
                int byte = row * 128 + kk * 64 + g * 16;
                byte ^= (row & 7) << 4;
                v8bf bk = *(const v8bf*)&ldsK[byte >> 1];
                s[n] = __builtin_amdgcn_mfma_f32_16x16x32_bf16(aq[kk], bk, s[n], 0, 0, 0);
            }
        #pragma unroll
        for (int n = 0; n < 4; ++n) {
            const int key = t0 + 16 * n + l16;
            #pragma unroll
            for (int r = 0; r < 4; ++r) {
                const int qq = qw + 4 * g + r;
                if (key <= qq)
                    colacc[n] += ex2(s[n][r] * (SCALE * LOG2E) - lse_r[r]);
            }
        }
    }
    #pragma unroll
    for (int n = 0; n < 4; ++n) {
        colacc[n] += __shfl_xor(colacc[n], 16);
        colacc[n] += __shfl_xor(colacc[n], 32);
    }
    if (lane < 16) {
        #pragma unroll
        for (int n = 0; n < 4; ++n)
            cs[wave][16 * n + lane] = colacc[n];
    }
    __syncthreads();
    if (tid < KT) {
        float v = cs[0][tid] + cs[1][tid] + cs[2][tid] + cs[3][tid];
        rsg[h * SEQ + t0 + tid] = v;
    }
}

extern "C" void kernel_launch(void* const* d_in, const int* in_sizes, int n_in,
                              void* d_out, int out_size, void* d_ws, size_t ws_size,
                              hipStream_t stream) {
    (void)in_sizes; (void)n_in; (void)out_size;
    const float* qg = (const float*)d_in[0];
    const float* kg = (const float*)d_in[1];
    const float* vg = (const float*)d_in[2];
    float* outg = (float*)d_out;
    float* rsg  = outg + (size_t)HEADS * SEQ * DIM;

    const size_t nElem   = (size_t)HEADS * SEQ * DIM;        // 4.19M
    const size_t lseB    = (size_t)HEADS * SEQ * sizeof(float);
    const size_t needB   = lseB + 3 * nElem * sizeof(__bf16);

    if (ws_size >= needB) {
        float*  lseg = (float*)d_ws;
        __bf16* Qb = (__bf16*)((char*)d_ws + lseB);
        __bf16* Kb = Qb + nElem;
        __bf16* Vb = Kb + nElem;
        conv_fused_kernel<<<dim3(SEQ / 64, HEADS, 3), 256, 0, stream>>>(
            qg, kg, vg, Qb, Kb, Vb);
        fa_fwd8_kernel<<<dim3(512), 512, 0, stream>>>(Qb, Kb, Vb, outg, lseg);
        fa_colsum8_kernel<<<dim3(512), 512, 0, stream>>>(Qb, Kb, lseg, rsg);
    } else {
        float* lseg = (float*)d_ws;
        dim3 grid(SEQ / QT, HEADS);
        fa_fwd_v1_kernel<<<grid, 256, 0, stream>>>(qg, kg, vg, outg, lseg);
        fa_colsum_v1_kernel<<<grid, 256, 0, stream>>>(qg, kg, lseg, rsg);
    }
}

// Round 15
// 94.401 us; speedup vs baseline: 1.0309x; 1.0309x over previous
//
#include <hip/hip_runtime.h>
#include <hip/hip_bf16.h>

#define HEADS 16
#define SEQ   4096
#define DIM   64
#define QT    64
#define KT    64
#define SCALE 0.125f
// SCALE * log2(e): folded into Q at conversion so scores are in log2 domain
#define CF    0.18033688011112042f
#define LOG2E 1.4426950408889634f

typedef __bf16 v8bf  __attribute__((ext_vector_type(8)));
typedef __bf16 v4bf  __attribute__((ext_vector_type(4)));
typedef float  f32x4 __attribute__((ext_vector_type(4)));

__device__ __forceinline__ __bf16 to_bf(float f) { return (__bf16)f; }
// v_exp_f32 computes 2^x; v_log_f32 computes log2(x)
__device__ __forceinline__ float ex2(float x) { return __builtin_amdgcn_exp2f(x); }
__device__ __forceinline__ float lg2(float x) { return __builtin_amdgcn_logf(x); }

__device__ __forceinline__ void gload16(const __bf16* g, __bf16* l) {
    __builtin_amdgcn_global_load_lds(
        (const __attribute__((address_space(1))) void*)g,
        (__attribute__((address_space(3))) void*)l,
        16, 0, 0);
}

// ===========================================================================
// Fused pre-pass (one launch): z=0 K [h][d][s] -> Kb [h][t][d];
// z=1 V [h][s][d] -> Vb [h][d][perm(t)]; z=2 Q scale-convert (CF folded).
// ===========================================================================
__global__ __launch_bounds__(256) void conv_fused_kernel(
    const float* __restrict__ qg, const float* __restrict__ kg,
    const float* __restrict__ vg, __bf16* __restrict__ Qb,
    __bf16* __restrict__ Kb, __bf16* __restrict__ Vb)
{
    __shared__ __bf16 ldsT[64][65];
    const int h   = blockIdx.y;
    const int t0  = blockIdx.x * 64;
    const int tid = threadIdx.x;
    const int rr  = tid >> 2;          // 0..63
    const int cq  = (tid & 3) * 16;    // 0,16,32,48

    if (blockIdx.z == 2) {
        const float* src = qg + ((size_t)h * SEQ + t0 + rr) * DIM + cq;
        __bf16* dst = Qb + ((size_t)h * SEQ + t0 + rr) * DIM + cq;
        v8bf o0, o1;
        #pragma unroll
        for (int j = 0; j < 2; ++j) {
            float4 f0 = *(const float4*)(src + 8 * j);
            float4 f1 = *(const float4*)(src + 8 * j + 4);
            v8bf o;
            o[0] = to_bf(f0.x * CF); o[1] = to_bf(f0.y * CF);
            o[2] = to_bf(f0.z * CF); o[3] = to_bf(f0.w * CF);
            o[4] = to_bf(f1.x * CF); o[5] = to_bf(f1.y * CF);
            o[6] = to_bf(f1.z * CF); o[7] = to_bf(f1.w * CF);
            if (j == 0) o0 = o; else o1 = o;
        }
        *(v8bf*)dst = o0;
        *(v8bf*)(dst + 8) = o1;
        return;
    }

    if (blockIdx.z == 0) {
        const float* src = kg + ((size_t)h * DIM + rr) * SEQ + t0 + cq;  // d=rr
        #pragma unroll
        for (int j = 0; j < 4; ++j) {
            float4 f = *(const float4*)(src + 4 * j);
            ldsT[rr][cq + 4 * j + 0] = to_bf(f.x);
            ldsT[rr][cq + 4 * j + 1] = to_bf(f.y);
            ldsT[rr][cq + 4 * j + 2] = to_bf(f.z);
            ldsT[rr][cq + 4 * j + 3] = to_bf(f.w);
        }
        __syncthreads();
        __bf16* dst = Kb + (size_t)h * SEQ * DIM + (size_t)(t0 + rr) * DIM + cq;
        v8bf o0, o1;
        #pragma unroll
        for (int i = 0; i < 8; ++i) {
            o0[i] = ldsT[cq + i][rr];
            o1[i] = ldsT[cq + 8 + i][rr];
        }
        *(v8bf*)dst = o0;
        *(v8bf*)(dst + 8) = o1;
    } else {
        const float* src = vg + ((size_t)h * SEQ + t0 + rr) * DIM + cq;  // t=rr
        #pragma unroll
        for (int j = 0; j < 4; ++j) {
            float4 f = *(const float4*)(src + 4 * j);
            ldsT[rr][cq + 4 * j + 0] = to_bf(f.x);
            ldsT[rr][cq + 4 * j + 1] = to_bf(f.y);
            ldsT[rr][cq + 4 * j + 2] = to_bf(f.z);
            ldsT[rr][cq + 4 * j + 3] = to_bf(f.w);
        }
        __syncthreads();
        __bf16* dst0 = Vb + ((size_t)h * DIM + rr) * SEQ + t0;
        const int n  = cq >> 4;
        const int c0 = 32 * (n >> 1) + 4 * (n & 1);
        #pragma unroll
        for (int j2 = 0; j2 < 4; ++j2) {
            v4bf ch;
            #pragma unroll
            for (int r = 0; r < 4; ++r)
                ch[r] = ldsT[cq + 4 * j2 + r][rr];
            *(v4bf*)(dst0 + c0 + 8 * j2) = ch;
        }
    }
}

// ===========================================================================
// Pass A (round-11/12 best, 53.2us measured): 8-wave blocks, intra-block
// key-split, both Q-groups share each ds_read, setprio MFMA clusters,
// LDS-scratch combine.
// ===========================================================================
__global__ __launch_bounds__(512, 4) void fa_fwd8_kernel(
    const __bf16* __restrict__ Qb, const __bf16* __restrict__ Kb,
    const __bf16* __restrict__ Vb, float* __restrict__ outg,
    float* __restrict__ lseg)
{
    const int b    = blockIdx.x;
    const int xcd  = b & 7;
    const int j    = b >> 3;           // 0..63
    const int h    = 2 * xcd + (j & 1);
    const int a    = j >> 1;           // 0..31: qtile pair (a, 63-a)
    const int tid  = threadIdx.x;      // 0..511
    const int wave = tid >> 6;         // 0..7
    const int lane = tid & 63;
    const int g    = lane >> 4;
    const int l16  = lane & 15;
    const int grp  = wave >> 2;        // 0: even subtiles; 1: odd subtiles
    const int w4   = wave & 3;
    const int wit  = w4 * 16 + l16;    // q-row within a qtile

    const int qlo = a;
    const int qhi = 63 - a;
    const int NT  = 64 - a;
    const int nIt = (NT + 1) >> 1;

    __shared__ alignas(16) __bf16 ldsPool[32768];

    const int r0 = tid >> 3;           // 0..63
    const int c0 = tid & 7;
    const size_t kOff = (size_t)r0 * DIM + (size_t)((c0 ^ (r0 & 7)) << 3);
    const size_t vOff = (size_t)r0 * SEQ + (size_t)((c0 ^ (r0 & 7)) << 3);
    const __bf16* KbH = Kb + (size_t)h * SEQ * DIM;
    const __bf16* VbH = Vb + (size_t)h * DIM * SEQ;
    const int ldsW = wave * 512;

    const int qLoRow = qlo * QT + wit;
    const int qHiRow = qhi * QT + wit;
    const __bf16* qlr = Qb + ((size_t)h * SEQ + qLoRow) * DIM + g * 8;
    const __bf16* qhr = Qb + ((size_t)h * SEQ + qHiRow) * DIM + g * 8;
    v8bf aqlo0 = *(const v8bf*)qlr;
    v8bf aqlo1 = *(const v8bf*)(qlr + 32);
    v8bf aqhi0 = *(const v8bf*)qhr;
    v8bf aqhi1 = *(const v8bf*)(qhr + 32);

    f32x4 accl[4], acch[4];
    #pragma unroll
    for (int n = 0; n < 4; ++n) {
        accl[n] = (f32x4){0.f, 0.f, 0.f, 0.f};
        acch[n] = (f32x4){0.f, 0.f, 0.f, 0.f};
    }
    float lpl[4] = {0.f, 0.f, 0.f, 0.f};
    float lph[4] = {0.f, 0.f, 0.f, 0.f};

    int cur = 0;
    #pragma unroll
    for (int u = 0; u < 2; ++u) {
        gload16(KbH + (size_t)(64 * u) * DIM + kOff,
                ldsPool + (size_t)u * 4096 + ldsW);
        gload16(VbH + 64 * u + vOff,
                ldsPool + 16384 + (size_t)u * 4096 + ldsW);
    }
    __syncthreads();

    #pragma unroll 1
    for (int it = 0; it < nIt; ++it) {
        if (it + 1 < nIt) {
            const int nbuf = cur ^ 1;
            #pragma unroll
            for (int u = 0; u < 2; ++u) {
                gload16(KbH + (size_t)(128 * (it + 1) + 64 * u) * DIM + kOff,
                        ldsPool + (size_t)(nbuf * 2 + u) * 4096 + ldsW);
                gload16(VbH + (128 * (it + 1) + 64 * u) + vOff,
                        ldsPool + 16384 + (size_t)(nbuf * 2 + u) * 4096 + ldsW);
            }
        }
        const int t = 2 * it + grp;
        if (t <= qhi) {
            const __bf16* Kt = ldsPool + (size_t)(cur * 2 + grp) * 4096;
            const __bf16* Vt = ldsPool + 16384 + (size_t)(cur * 2 + grp) * 4096;
            if (t <= qlo) {
                f32x4 sl[4], sh[4];
                #pragma unroll
                for (int n = 0; n < 4; ++n) {
                    sl[n] = (f32x4){0.f, 0.f, 0.f, 0.f};
                    sh[n] = (f32x4){0.f, 0.f, 0.f, 0.f};
                }
                __builtin_amdgcn_s_setprio(1);
                #pragma unroll
                for (int kk = 0; kk < 2; ++kk) {
                    #pragma unroll
                    for (int n = 0; n < 4; ++n) {
                        int row  = 16 * n + l16;
                        int byte = row * 128 + kk * 64 + g * 16;
                        byte ^= (row & 7) << 4;
                        v8bf ak = *(const v8bf*)&Kt[byte >> 1];
                        sl[n] = __builtin_amdgcn_mfma_f32_16x16x32_bf16(
                            ak, kk ? aqlo1 : aqlo0, sl[n], 0, 0, 0);
                        sh[n] = __builtin_amdgcn_mfma_f32_16x16x32_bf16(
                            ak, kk ? aqhi1 : aqhi0, sh[n], 0, 0, 0);
                    }
                }
                __builtin_amdgcn_s_setprio(0);
                if (t == qlo) {
                    #pragma unroll
                    for (int n = 0; n < 4; ++n)
                        #pragma unroll
                        for (int r = 0; r < 4; ++r)
                            if (16 * n + 4 * g + r > wit) sl[n][r] = -3.0e38f;
                }
                v8bf pl0, pl1, ph0, ph1;
                #pragma unroll
                for (int n = 0; n < 4; ++n) {
                    #pragma unroll
                    for (int r = 0; r < 4; ++r) {
                        float p = ex2(sl[n][r]);
                        float q = ex2(sh[n][r]);
                        lpl[r] += p;
                        lph[r] += q;
                        if (n < 2) { pl0[(n & 1) * 4 + r] = to_bf(p);
                                     ph0[(n & 1) * 4 + r] = to_bf(q); }
                        else       { pl1[(n & 1) * 4 + r] = to_bf(p);
                                     ph1[(n & 1) * 4 + r] = to_bf(q); }
                    }
                }
                __builtin_amdgcn_s_setprio(1);
                #pragma unroll
                for (int kk = 0; kk < 2; ++kk) {
                    #pragma unroll
                    for (int n = 0; n < 4; ++n) {
                        int row  = 16 * n + l16;
                        int byte = row * 128 + kk * 64 + g * 16;
                        byte ^= (row & 7) << 4;
                        v8bf av = *(const v8bf*)&Vt[byte >> 1];
                        accl[n] = __builtin_amdgcn_mfma_f32_16x16x32_bf16(
                            av, kk ? pl1 : pl0, accl[n], 0, 0, 0);
                        acch[n] = __builtin_amdgcn_mfma_f32_16x16x32_bf16(
                            av, kk ? ph1 : ph0, acch[n], 0, 0, 0);
                    }
                }
                __builtin_amdgcn_s_setprio(0);
            } else {
                f32x4 sh[4];
                #pragma unroll
                for (int n = 0; n < 4; ++n) sh[n] = (f32x4){0.f, 0.f, 0.f, 0.f};
                __builtin_amdgcn_s_setprio(1);
                #pragma unroll
                for (int kk = 0; kk < 2; ++kk) {
                    #pragma unroll
                    for (int n = 0; n < 4; ++n) {
                        int row  = 16 * n + l16;
                        int byte = row * 128 + kk * 64 + g * 16;
                        byte ^= (row & 7) << 4;
                        v8bf ak = *(const v8bf*)&Kt[byte >> 1];
                        sh[n] = __builtin_amdgcn_mfma_f32_16x16x32_bf16(
                            ak, kk ? aqhi1 : aqhi0, sh[n], 0, 0, 0);
                    }
                }
                __builtin_amdgcn_s_setprio(0);
                if (t == qhi) {
                    #pragma unroll
                    for (int n = 0; n < 4; ++n)
                        #pragma unroll
                        for (int r = 0; r < 4; ++r)
                            if (16 * n + 4 * g + r > wit) sh[n][r] = -3.0e38f;
                }
                v8bf ph0, ph1;
                #pragma unroll
                for (int n = 0; n < 4; ++n) {
                    #pragma unroll
                    for (int r = 0; r < 4; ++r) {
                        float q = ex2(sh[n][r]);
                        lph[r] += q;
                        if (n < 2) ph0[(n & 1) * 4 + r] = to_bf(q);
                        else       ph1[(n & 1) * 4 + r] = to_bf(q);
                    }
                }
                __builtin_amdgcn_s_setprio(1);
                #pragma unroll
                for (int kk = 0; kk < 2; ++kk) {
                    #pragma unroll
                    for (int n = 0; n < 4; ++n) {
                        int row  = 16 * n + l16;
                        int byte = row * 128 + kk * 64 + g * 16;
                        byte ^= (row & 7) << 4;
                        v8bf av = *(const v8bf*)&Vt[byte >> 1];
                        acch[n] = __builtin_amdgcn_mfma_f32_16x16x32_bf16(
                            av, kk ? ph1 : ph0, acch[n], 0, 0, 0);
                    }
                }
                __builtin_amdgcn_s_setprio(0);
            }
        }
        __syncthreads();
        cur ^= 1;
    }

    // ---- combine partials across the grp pair through LDS scratch
    float* scratch = (float*)ldsPool;
    {
        float* sp = scratch + (size_t)(grp ? (4 + w4) : w4) * 1280;
        if (grp == 0) {
            #pragma unroll
            for (int n = 0; n < 4; ++n)
                #pragma unroll
                for (int r = 0; r < 4; ++r)
                    sp[(n * 4 + r) * 64 + lane] = acch[n][r];
            #pragma unroll
            for (int r = 0; r < 4; ++r) sp[(16 + r) * 64 + lane] = lph[r];
        } else {
            #pragma unroll
            for (int n = 0; n < 4; ++n)
                #pragma unroll
                for (int r = 0; r < 4; ++r)
                    sp[(n * 4 + r) * 64 + lane] = accl[n][r];
            #pragma unroll
            for (int r = 0; r < 4; ++r) sp[(16 + r) * 64 + lane] = lpl[r];
        }
    }
    __syncthreads();
    f32x4 accO[4];
    float lpO[4];
    {
        const float* op = scratch + (size_t)(grp ? w4 : (4 + w4)) * 1280;
        if (grp == 0) {
            #pragma unroll
            for (int n = 0; n < 4; ++n)
                #pragma unroll
                for (int r = 0; r < 4; ++r)
                    accO[n][r] = accl[n][r] + op[(n * 4 + r) * 64 + lane];
            #pragma unroll
            for (int r = 0; r < 4; ++r)
                lpO[r] = lpl[r] + op[(16 + r) * 64 + lane];
        } else {
            #pragma unroll
            for (int n = 0; n < 4; ++n)
                #pragma unroll
                for (int r = 0; r < 4; ++r)
                    accO[n][r] = acch[n][r] + op[(n * 4 + r) * 64 + lane];
            #pragma unroll
            for (int r = 0; r < 4; ++r)
                lpO[r] = lph[r] + op[(16 + r) * 64 + lane];
        }
    }

    const int q = (grp ? qhi : qlo) * QT + wit;
    float l = (lpO[0] + lpO[1]) + (lpO[2] + lpO[3]);
    l += __shfl_xor(l, 16);
    l += __shfl_xor(l, 32);
    const float inv = 1.0f / l;
    float* orow = outg + ((size_t)h * SEQ + q) * DIM;
    #pragma unroll
    for (int n = 0; n < 4; ++n) {
        f32x4 o = accO[n];
        o[0] *= inv; o[1] *= inv; o[2] *= inv; o[3] *= inv;
        *(f32x4*)(orow + 16 * n + 4 * g) = o;
    }
    if (g == 0)
        lseg[h * SEQ + q] = lg2(l);
}

// ===========================================================================
// Pass B (round-12 best): 8-wave colsum. Waves grp=0 take even qt, grp=1
// odd; w4 owns the 16-row q-slice. setprio MFMA clusters. 8-way LDS reduce.
// ===========================================================================
__global__ __launch_bounds__(512, 4) void fa_colsum8_kernel(
    const __bf16* __restrict__ Qb, const __bf16* __restrict__ Kb,
    const float* __restrict__ lseg, float* __restrict__ rsg)
{
    const int b    = blockIdx.x;
    const int xcd  = b & 7;
    const int j    = b >> 3;
    const int h    = 2 * xcd + (j & 1);
    const int ta   = j >> 1;            // 0..31
    const int tb   = 63 - ta;
    const int tid  = threadIdx.x;       // 0..511
    const int wave = tid >> 6;          // 0..7
    const int lane = tid & 63;
    const int g    = lane >> 4;
    const int l16  = lane & 15;
    const int grp  = wave >> 2;         // qt parity
    const int w4   = wave & 3;          // q-slice within qtile

    __shared__ alignas(16) __bf16 ldsK2[2][KT * DIM];   // 16 KB
    __shared__ float cs[2][8][KT];                      // 4 KB

    const int r0 = tid >> 3;            // 0..63
    const int c0 = tid & 7;
    const size_t kOff = (size_t)r0 * DIM + (size_t)((c0 ^ (r0 & 7)) << 3);
    const __bf16* KbH = Kb + (size_t)h * SEQ * DIM;
    const int ldsW = wave * 512;

    gload16(KbH + (size_t)ta * KT * DIM + kOff, &ldsK2[0][ldsW]);
    gload16(KbH + (size_t)tb * KT * DIM + kOff, &ldsK2[1][ldsW]);
    __syncthreads();

    float accA[4] = {0.f, 0.f, 0.f, 0.f};
    float accB[4] = {0.f, 0.f, 0.f, 0.f};

    #pragma unroll 1
    for (int qt = ta + grp; qt < SEQ / QT; qt += 2) {
        const int qw = qt * QT + w4 * 16;
        const __bf16* qrow = Qb + ((size_t)h * SEQ + qw + l16) * DIM + g * 8;
        v8bf aq0 = *(const v8bf*)qrow;
        v8bf aq1 = *(const v8bf*)(qrow + 32);
        float4 lse4 = *(const float4*)(lseg + (size_t)h * SEQ + qw + 4 * g);

        // ---- tile A (always active; qt >= ta by construction)
        {
            f32x4 s[4];
            #pragma unroll
            for (int n = 0; n < 4; ++n) s[n] = (f32x4){0.f, 0.f, 0.f, 0.f};
            __builtin_amdgcn_s_setprio(1);
            #pragma unroll
            for (int kk = 0; kk < 2; ++kk)
                #pragma unroll
                for (int n = 0; n < 4; ++n) {
                    int row  = 16 * n + l16;
                    int byte = row * 128 + kk * 64 + g * 16;
                    byte ^= (row & 7) << 4;
                    v8bf bk = *(const v8bf*)&ldsK2[0][byte >> 1];
                    s[n] = __builtin_amdgcn_mfma_f32_16x16x32_bf16(
                        kk ? aq1 : aq0, bk, s[n], 0, 0, 0);
                }
            __builtin_amdgcn_s_setprio(0);
            if (qt == ta) {
                #pragma unroll
                for (int n = 0; n < 4; ++n) {
                    const int key = ta * KT + 16 * n + l16;
                    #pragma unroll
                    for (int r = 0; r < 4; ++r) {
                        float e = ex2(s[n][r] - lse4[r]);
                        accA[n] += (key <= qw + 4 * g + r) ? e : 0.f;
                    }
                }
            } else {
                #pragma unroll
                for (int n = 0; n < 4; ++n)
                    #pragma unroll
                    for (int r = 0; r < 4; ++r)
                        accA[n] += ex2(s[n][r] - lse4[r]);
            }
        }
        // ---- tile B (active for qt >= tb)
        if (qt >= tb) {
            f32x4 s[4];
            #pragma unroll
            for (int n = 0; n < 4; ++n) s[n] = (f32x4){0.f, 0.f, 0.f, 0.f};
            __builtin_amdgcn_s_setprio(1);
            #pragma unroll
            for (int kk = 0; kk < 2; ++kk)
                #pragma unroll
                for (int n = 0; n < 4; ++n) {
                    int row  = 16 * n + l16;
                    int byte = row * 128 + kk * 64 + g * 16;
                    byte ^= (row & 7) << 4;
                    v8bf bk = *(const v8bf*)&ldsK2[1][byte >> 1];
                    s[n] = __builtin_amdgcn_mfma_f32_16x16x32_bf16(
                        kk ? aq1 : aq0, bk, s[n], 0, 0, 0);
                }
            __builtin_amdgcn_s_setprio(0);
            if (qt == tb) {
                #pragma unroll
                for (int n = 0; n < 4; ++n) {
                    const int key = tb * KT + 16 * n + l16;
                    #pragma unroll
                    for (int r = 0; r < 4; ++r) {
                        float e = ex2(s[n][r] - lse4[r]);
                        accB[n] += (key <= qw + 4 * g + r) ? e : 0.f;
                    }
                }
            } else {
                #pragma unroll
                for (int n = 0; n < 4; ++n)
                    #pragma unroll
                    for (int r = 0; r < 4; ++r)
                        accB[n] += ex2(s[n][r] - lse4[r]);
            }
        }
    }

    #pragma unroll
    for (int n = 0; n < 4; ++n) {
        accA[n] += __shfl_xor(accA[n], 16);
        accA[n] += __shfl_xor(accA[n], 32);
        accB[n] += __shfl_xor(accB[n], 16);
        accB[n] += __shfl_xor(accB[n], 32);
    }
    if (lane < 16) {
        #pragma unroll
        for (int n = 0; n < 4; ++n) {
            cs[0][wave][16 * n + lane] = accA[n];
            cs[1][wave][16 * n + lane] = accB[n];
        }
    }
    __syncthreads();
    if (tid < KT) {
        float v = 0.f;
        #pragma unroll
        for (int w = 0; w < 8; ++w) v += cs[0][w][tid];
        rsg[(size_t)h * SEQ + ta * KT + tid] = v;
    } else if (tid < 2 * KT) {
        const int t = tid - KT;
        float v = 0.f;
        #pragma unroll
        for (int w = 0; w < 8; ++w) v += cs[1][w][t];
        rsg[(size_t)h * SEQ + tb * KT + t] = v;
    }
}

// ===========================================================================
// Fallback (round-1, fp32 inputs, scalar staging) — used if ws too small.
// ===========================================================================
__global__ __launch_bounds__(256, 1) void fa_fwd_v1_kernel(
    const float* __restrict__ qg, const float* __restrict__ kg,
    const float* __restrict__ vg, float* __restrict__ outg,
    float* __restrict__ lseg)
{
    const int h    = blockIdx.y;
    const int q0   = blockIdx.x * QT;
    const int tid  = threadIdx.x;
    const int wave = tid >> 6;
    const int lane = tid & 63;
    const int g    = lane >> 4;
    const int l16  = lane & 15;

    __shared__ alignas(16) __bf16 ldsK[KT * DIM];
    __shared__ alignas(16) __bf16 ldsV[DIM * KT];
    __shared__ alignas(16) __bf16 ldsP[4][16 * 72];

    const int qw = q0 + wave * 16;
    v8bf aq[2];
    {
        const float* qrow = qg + ((size_t)h * SEQ + qw + l16) * DIM;
        #pragma unroll
        for (int kk = 0; kk < 2; ++kk) {
            const float* p = qrow + kk * 32 + g * 8;
            float4 f0 = *(const float4*)p;
            float4 f1 = *(const float4*)(p + 4);
            aq[kk][0] = to_bf(f0.x); aq[kk][1] = to_bf(f0.y);
            aq[kk][2] = to_bf(f0.z); aq[kk][3] = to_bf(f0.w);
            aq[kk][4] = to_bf(f1.x); aq[kk][5] = to_bf(f1.y);
            aq[kk][6] = to_bf(f1.z); aq[kk][7] = to_bf(f1.w);
        }
    }
    f32x4 acc[4];
    #pragma unroll
    for (int n = 0; n < 4; ++n) acc[n] = (f32x4){0.f, 0.f, 0.f, 0.f};
    float m_r[4], l_r[4];
    #pragma unroll
    for (int r = 0; r < 4; ++r) { m_r[r] = -__builtin_inff(); l_r[r] = 0.f; }

    const int ntiles = q0 / KT + 1;
    const int kd = tid >> 2;
    const int kc = (tid & 3) * 16;

    for (int t = 0; t < ntiles; ++t) {
        const int t0 = t * KT;
        __syncthreads();
        {
            const float* src = kg + ((size_t)h * DIM + kd) * SEQ + t0 + kc;
            #pragma unroll
            for (int j = 0; j < 4; ++j) {
                float4 f = *(const float4*)(src + 4 * j);
                #pragma unroll
                for (int i = 0; i < 4; ++i) {
                    int row  = kc + 4 * j + i;
                    int byte = row * 128 + kd * 2;
                    byte ^= (row & 7) << 4;
                    ldsK[byte >> 1] = to_bf(((const float*)&f)[i]);
                }
            }
        }
        {
            const float* src = vg + ((size_t)h * SEQ + t0 + kd) * DIM + kc;
            #pragma unroll
            for (int j = 0; j < 4; ++j) {
                float4 f = *(const float4*)(src + 4 * j);
                #pragma unroll
                for (int i = 0; i < 4; ++i) {
                    int row  = kc + 4 * j + i;
                    int byte = row * 128 + kd * 2;
                    byte ^= (row & 7) << 4;
                    ldsV[byte >> 1] = to_bf(((const float*)&f)[i]);
                }
            }
        }
        __syncthreads();

        f32x4 s[4];
        #pragma unroll
        for (int n = 0; n < 4; ++n) s[n] = (f32x4){0.f, 0.f, 0.f, 0.f};
        #pragma unroll
        for (int kk = 0; kk < 2; ++kk)
            #pragma unroll
            for (int n = 0; n < 4; ++n) {
                int row  = 16 * n + l16;
                int byte = row * 128 + kk * 64 + g * 16;
                byte ^= (row & 7) << 4;
                v8bf bk = *(const v8bf*)&ldsK[byte >> 1];
                s[n] = __builtin_amdgcn_mfma_f32_16x16x32_bf16(aq[kk], bk, s[n], 0, 0, 0);
            }
        float pvv[4][4];
        #pragma unroll
        for (int r = 0; r < 4; ++r) {
            const int qq = qw + 4 * g + r;
            float sv[4];
            #pragma unroll
            for (int n = 0; n < 4; ++n) {
                int key = t0 + 16 * n + l16;
                sv[n] = (key <= qq) ? s[n][r] * (SCALE * LOG2E) : -3.0e38f;
            }
            float mx = fmaxf(fmaxf(sv[0], sv[1]), fmaxf(sv[2], sv[3]));
            mx = fmaxf(mx, __shfl_xor(mx, 1));
            mx = fmaxf(mx, __shfl_xor(mx, 2));
            mx = fmaxf(mx, __shfl_xor(mx, 4));
            mx = fmaxf(mx, __shfl_xor(mx, 8));
            float mnew = fmaxf(m_r[r], mx);
            float corr = ex2(m_r[r] - mnew);
            m_r[r] = mnew;
            float rs = 0.f;
            #pragma unroll
            for (int n = 0; n < 4; ++n) {
                float p = (sv[n] > -1.0e38f) ? ex2(sv[n] - mnew) : 0.f;
                pvv[n][r] = p;
                rs += p;
            }
            rs += __shfl_xor(rs, 1);
            rs += __shfl_xor(rs, 2);
            rs += __shfl_xor(rs, 4);
            rs += __shfl_xor(rs, 8);
            l_r[r] = l_r[r] * corr + rs;
            #pragma unroll
            for (int n = 0; n < 4; ++n) acc[n][r] *= corr;
        }
        #pragma unroll
        for (int n = 0; n < 4; ++n)
            #pragma unroll
            for (int r = 0; r < 4; ++r)
                ldsP[wave][(4 * g + r) * 72 + 16 * n + l16] = to_bf(pvv[n][r]);
        asm volatile("s_waitcnt lgkmcnt(0)" ::: "memory");
        __builtin_amdgcn_sched_barrier(0);
        #pragma unroll
        for (int kk = 0; kk < 2; ++kk) {
            v8bf ap = *(const v8bf*)&ldsP[wave][l16 * 72 + 32 * kk + 8 * g];
            #pragma unroll
            for (int n = 0; n < 4; ++n) {
                int row  = 16 * n + l16;
                int byte = row * 128 + kk * 64 + g * 16;
                byte ^= (row & 7) << 4;
                v8bf bv = *(const v8bf*)&ldsV[byte >> 1];
                acc[n] = __builtin_amdgcn_mfma_f32_16x16x32_bf16(ap, bv, acc[n], 0, 0, 0);
            }
        }
    }
    #pragma unroll
    for (int r = 0; r < 4; ++r) {
        const int qq  = qw + 4 * g + r;
        const float inv = 1.0f / l_r[r];
        float* orow = outg + ((size_t)h * SEQ + qq) * DIM;
        #pragma unroll
        for (int n = 0; n < 4; ++n)
            orow[16 * n + l16] = acc[n][r] * inv;
        if (l16 == 0)
            lseg[h * SEQ + qq] = m_r[r] + lg2(l_r[r]);
    }
}

__global__ __launch_bounds__(256, 1) void fa_colsum_v1_kernel(
    const float* __restrict__ qg, const float* __restrict__ kg,
    const float* __restrict__ lseg, float* __restrict__ rsg)
{
    const int h    = blockIdx.y;
    const int t0   = blockIdx.x * KT;
    const int tid  = threadIdx.x;
    const int wave = tid >> 6;
    const int lane = tid & 63;
    const int g    = lane >> 4;
    const int l16  = lane & 15;

    __shared__ alignas(16) __bf16 ldsK[KT * DIM];
    __shared__ float cs[4][KT];
    {
        const int kd = tid >> 2;
        const int kc = (tid & 3) * 16;
        const float* src = kg + ((size_t)h * DIM + kd) * SEQ + t0 + kc;
        #pragma unroll
        for (int j = 0; j < 4; ++j) {
            float4 f = *(const float4*)(src + 4 * j);
            #pragma unroll
            for (int i = 0; i < 4; ++i) {
                int row  = kc + 4 * j + i;
                int byte = row * 128 + kd * 2;
                byte ^= (row & 7) << 4;
                ldsK[byte >> 1] = to_bf(((const float*)&f)[i]);
            }
        }
    }
    __syncthreads();
    float colacc[4] = {0.f, 0.f, 0.f, 0.f};
    for (int qt = t0 / QT; qt < SEQ / QT; ++qt) {
        const int qw = qt * QT + wave * 16;
        const float* qrow = qg + ((size_t)h * SEQ + qw + l16) * DIM;
        v8bf aq[2];
        #pragma unroll
        for (int kk = 0; kk < 2; ++kk) {
            const float* p = qrow + kk * 32 + g * 8;
            float4 f0 = *(const float4*)p;
            float4 f1 = *(const float4*)(p + 4);
            aq[kk][0] = to_bf(f0.x); aq[kk][1] = to_bf(f0.y);
            aq[kk][2] = to_bf(f0.z); aq[kk][3] = to_bf(f0.w);
            aq[kk][4] = to_bf(f1.x); aq[kk][5] = to_bf(f1.y);
            aq[kk][6] = to_bf(f1.z); aq[kk][7] = to_bf(f1.w);
        }
        float lse_r[4];
        #pragma unroll
        for (int r = 0; r < 4; ++r)
            lse_r[r] = lseg[h * SEQ + qw + 4 * g + r];
        f32x4 s[4];
        #pragma unroll
        for (int n = 0; n < 4; ++n) s[n] = (f32x4){0.f, 0.f, 0.f, 0.f};
        #pragma unroll
        for (int kk = 0; kk < 2; ++kk)
            #pragma unroll
            for (int n = 0; n < 4; ++n) {
                int row  = 16 * n + l16;
                int byte = row * 128 + kk * 64 + g * 16;
                byte ^= (row & 7) << 4;
                v8bf bk = *(const v8bf*)&ldsK[byte >> 1];
                s[n] = __builtin_amdgcn_mfma_f32_16x16x32_bf16(aq[kk], bk, s[n], 0, 0, 0);
            }
        #pragma unroll
        for (int n = 0; n < 4; ++n) {
            const int key = t0 + 16 * n + l16;
            #pragma unroll
            for (int r = 0; r < 4; ++r) {
                const int qq = qw + 4 * g + r;
                if (key <= qq)
                    colacc[n] += ex2(s[n][r] * (SCALE * LOG2E) - lse_r[r]);
            }
        }
    }
    #pragma unroll
    for (int n = 0; n < 4; ++n) {
        colacc[n] += __shfl_xor(colacc[n], 16);
        colacc[n] += __shfl_xor(colacc[n], 32);
    }
    if (lane < 16) {
        #pragma unroll
        for (int n = 0; n < 4; ++n)
            cs[wave][16 * n + lane] = colacc[n];
    }
    __syncthreads();
    if (tid < KT) {
        float v = cs[0][tid] + cs[1][tid] + cs[2][tid] + cs[3][tid];
        rsg[h * SEQ + t0 + tid] = v;
    }
}

extern "C" void kernel_launch(void* const* d_in, const int* in_sizes, int n_in,
                              void* d_out, int out_size, void* d_ws, size_t ws_size,
                              hipStream_t stream) {
    (void)in_sizes; (void)n_in; (void)out_size;
    const float* qg = (const float*)d_in[0];
    const float* kg = (const float*)d_in[1];
    const float* vg = (const float*)d_in[2];
    float* outg = (float*)d_out;
    float* rsg  = outg + (size_t)HEADS * SEQ * DIM;

    const size_t nElem   = (size_t)HEADS * SEQ * DIM;        // 4.19M
    const size_t lseB    = (size_t)HEADS * SEQ * sizeof(float);
    const size_t needB   = lseB + 3 * nElem * sizeof(__bf16);

    if (ws_size >= needB) {
        float*  lseg = (float*)d_ws;
        __bf16* Qb = (__bf16*)((char*)d_ws + lseB);
        __bf16* Kb = Qb + nElem;
        __bf16* Vb = Kb + nElem;
        conv_fused_kernel<<<dim3(SEQ / 64, HEADS, 3), 256, 0, stream>>>(
            qg, kg, vg, Qb, Kb, Vb);
        fa_fwd8_kernel<<<dim3(512), 512, 0, stream>>>(Qb, Kb, Vb, outg, lseg);
        fa_colsum8_kernel<<<dim3(512), 512, 0, stream>>>(Qb, Kb, lseg, rsg);
    } else {
        float* lseg = (float*)d_ws;
        dim3 grid(SEQ / QT, HEADS);
        fa_fwd_v1_kernel<<<grid, 256, 0, stream>>>(qg, kg, vg, outg, lseg);
        fa_colsum_v1_kernel<<<grid, 256, 0, stream>>>(qg, kg, lseg, rsg);
    }
}